// Round 1
// baseline (1393.271 us; speedup 1.0000x reference)
//
#include <hip/hip_runtime.h>

#define LL 784
#define CHI 128
#define CLS 10
#define BATCH 1024
#define BC 16            // batch rows per block
#define NBLK (BATCH/BC)  // 64 blocks

typedef __attribute__((ext_vector_type(8))) short short8;
typedef __attribute__((ext_vector_type(4))) float floatx4;

__device__ inline unsigned int f2bf(float v) {
    unsigned int u = __float_as_uint(v);
    u += 0x7fffu + ((u >> 16) & 1u);   // round-to-nearest-even
    return u >> 16;
}

// ---------------------------------------------------------------------------
// prep: W fp32 (L,2,CHI,CHI) -> ws bf16, pre-swizzled into MFMA B-fragment
// order.  ws layout: ushort ws[L][64 frags][64 lanes][8 elems]
//   frag f = kt*8 + nt   (kt: K-tile of 32, nt: N-tile of 16)
//   lane l: n-col = nt*16 + (l&15), k = kt*32 + (l>>4)*8 + j
//   k = s*128 + a  ->  s = kt>>2, a = (kt&3)*32 + (l>>4)*8 + j
// ---------------------------------------------------------------------------
__global__ __launch_bounds__(256) void prep_kernel(const float* __restrict__ W,
                                                   unsigned int* __restrict__ ws4) {
    int T = blockIdx.x * 256 + threadIdx.x;   // [0, LL*4096)
    int n   = T >> 12;
    int rem = T & 4095;
    int f = rem >> 6;
    int l = rem & 63;
    int kt = f >> 3, nt = f & 7;
    int s = kt >> 2;
    int abase = (kt & 3) * 32 + (l >> 4) * 8;
    int c = nt * 16 + (l & 15);
    const float* Wp = W + ((size_t)(n * 2 + s) * CHI + abase) * CHI + c;
    unsigned int v0 = f2bf(Wp[0 * CHI]) | (f2bf(Wp[1 * CHI]) << 16);
    unsigned int v1 = f2bf(Wp[2 * CHI]) | (f2bf(Wp[3 * CHI]) << 16);
    unsigned int v2 = f2bf(Wp[4 * CHI]) | (f2bf(Wp[5 * CHI]) << 16);
    unsigned int v3 = f2bf(Wp[6 * CHI]) | (f2bf(Wp[7 * CHI]) << 16);
    uint4 pk; pk.x = v0; pk.y = v1; pk.z = v2; pk.w = v3;
    ((uint4*)ws4)[T] = pk;                    // fully coalesced 16B stores
}

// ---------------------------------------------------------------------------
// main: 64 blocks x 256 threads (4 waves). Block owns 16 batch rows.
// h[16][128] fp32 in LDS (row stride 132 to break bank conflicts).
// Per site: B-frags via global_load_dwordx4 from ws (registers, no LDS),
// A-frags = bf16(x_s * h) built from LDS, 16 MFMAs/wave n-split, h += delta.
// ---------------------------------------------------------------------------
__global__ __launch_bounds__(256) void mps_kernel(const float* __restrict__ x,
                                                  const float* __restrict__ W,
                                                  const unsigned short* __restrict__ ws,
                                                  const float* __restrict__ V,
                                                  float* __restrict__ out,
                                                  int fast) {
    __shared__ float hsh[BC * 132];
    const int t = threadIdx.x;
    const int w = t >> 6, l = t & 63;
    const int lane16 = l & 15, q = l >> 4;
    const int rb = blockIdx.x * BC;

    for (int i = t; i < BC * 132; i += 256) hsh[i] = 1.0f;
    __syncthreads();

    // this lane's batch row (for A fragments) is m = lane16
    const float* xrow = x + (size_t)(rb + lane16) * (2 * LL);

    for (int n = 0; n < LL; n++) {
        // ---- B fragments (16 x global_load_dwordx4 per wave) ----
        short8 bfr[8][2];
        if (fast) {
            const unsigned short* wsn = ws + (size_t)n * 32768;
            #pragma unroll
            for (int kt = 0; kt < 8; kt++) {
                #pragma unroll
                for (int ntl = 0; ntl < 2; ntl++) {
                    int f = kt * 8 + (w * 2 + ntl);
                    bfr[kt][ntl] = *(const short8*)(wsn + ((f << 6) + l) * 8);
                }
            }
        } else {
            // fallback: gather fp32 W directly (slow but correct)
            #pragma unroll
            for (int kt = 0; kt < 8; kt++) {
                int s = kt >> 2;
                int abase = (kt & 3) * 32 + q * 8;
                #pragma unroll
                for (int ntl = 0; ntl < 2; ntl++) {
                    int c = (w * 2 + ntl) * 16 + lane16;
                    const float* Wp = W + ((size_t)(n * 2 + s) * CHI + abase) * CHI + c;
                    short8 bb;
                    #pragma unroll
                    for (int j = 0; j < 8; j++) bb[j] = (short)f2bf(Wp[j * CHI]);
                    bfr[kt][ntl] = bb;
                }
            }
        }

        // ---- x for this lane's row at this site ----
        float x0 = xrow[n];
        float x1 = xrow[LL + n];

        // ---- A fragments from LDS h ----
        float hreg[4][8];
        #pragma unroll
        for (int kk = 0; kk < 4; kk++) {
            int base = lane16 * 132 + kk * 32 + q * 8;
            #pragma unroll
            for (int j = 0; j < 8; j++) hreg[kk][j] = hsh[base + j];
        }
        short8 afr[8];
        #pragma unroll
        for (int kt = 0; kt < 8; kt++) {
            float xv = (kt >> 2) ? x1 : x0;
            int kk = kt & 3;
            short8 aa;
            #pragma unroll
            for (int j = 0; j < 8; j++) aa[j] = (short)f2bf(xv * hreg[kk][j]);
            afr[kt] = aa;
        }

        __syncthreads();   // all waves done READING h_old

        // ---- MFMA: delta = A * B, n-split (wave w owns cols [w*32, w*32+32)) ----
        floatx4 acc[2];
        acc[0] = (floatx4){0.f, 0.f, 0.f, 0.f};
        acc[1] = (floatx4){0.f, 0.f, 0.f, 0.f};
        #pragma unroll
        for (int kt = 0; kt < 8; kt++) {
            acc[0] = __builtin_amdgcn_mfma_f32_16x16x32_bf16(afr[kt], bfr[kt][0], acc[0], 0, 0, 0);
            acc[1] = __builtin_amdgcn_mfma_f32_16x16x32_bf16(afr[kt], bfr[kt][1], acc[1], 0, 0, 0);
        }

        // ---- h += delta  (C layout: col = lane&15, row = q*4 + reg) ----
        #pragma unroll
        for (int ntl = 0; ntl < 2; ntl++) {
            int c = (w * 2 + ntl) * 16 + lane16;
            #pragma unroll
            for (int i = 0; i < 4; i++) {
                int idx = (q * 4 + i) * 132 + c;
                hsh[idx] += acc[ntl][i];
            }
        }
        __syncthreads();   // h_new visible before next site's reads
    }

    // ---- logits = h @ V ----
    if (t < BC * CLS) {
        int r = t / CLS, cls = t % CLS;
        float sum = 0.f;
        for (int a = 0; a < CHI; a++) sum += hsh[r * 132 + a] * V[a * CLS + cls];
        out[(size_t)(rb + r) * CLS + cls] = sum;
    }
}

extern "C" void kernel_launch(void* const* d_in, const int* in_sizes, int n_in,
                              void* d_out, int out_size, void* d_ws, size_t ws_size,
                              hipStream_t stream) {
    const float* x = (const float*)d_in[0];
    const float* W = (const float*)d_in[1];
    const float* V = (const float*)d_in[2];
    float* out = (float*)d_out;

    const size_t need = (size_t)LL * 64 * 64 * 16;   // 51,380,224 B
    int fast = (ws_size >= need) ? 1 : 0;

    if (fast) {
        prep_kernel<<<LL * 16, 256, 0, stream>>>(W, (unsigned int*)d_ws);
    }
    mps_kernel<<<NBLK, 256, 0, stream>>>(x, W, (const unsigned short*)d_ws, V, out, fast);
}

// Round 2
// 764.548 us; speedup vs baseline: 1.8223x; 1.8223x over previous
//
#include <hip/hip_runtime.h>

#define LL 784
#define CHI 128
#define CLS 10
#define BC 16
#define NBLK 64          // 1024/16
#define HS 132           // h row stride in floats (pad breaks 4-way conflicts)

typedef __attribute__((ext_vector_type(8))) short short8;
typedef __attribute__((ext_vector_type(4))) float floatx4;

__device__ inline unsigned int f2bf(float v) {
    unsigned int u = __float_as_uint(v);
    u += 0x7fffu + ((u >> 16) & 1u);   // RNE
    return u >> 16;
}

// workgroup barrier that does NOT drain vmcnt — keeps W prefetch in flight.
__device__ inline void lds_barrier() {
    asm volatile("s_waitcnt lgkmcnt(0)\n\ts_barrier" ::: "memory");
}

// ---------------------------------------------------------------------------
// prep: W fp32 (L,2,CHI,CHI) -> bf16 MFMA B-fragments, grouped so each wave's
// per-site stream is one contiguous 8KB block.
// frag index F = nt*8 + s*4 + kt ; lane l, elem j:
//   value = W[n][s][a = kt*32 + (l>>4)*8 + j][c = nt*16 + (l&15)]
// ws layout: ushort ws[L][64 frags][64 lanes][8]
// ---------------------------------------------------------------------------
__global__ __launch_bounds__(256) void prep_kernel(const float* __restrict__ W,
                                                   uint4* __restrict__ ws4) {
    int T = blockIdx.x * 256 + threadIdx.x;   // [0, LL*4096)
    int n   = T >> 12;
    int rem = T & 4095;
    int F = rem >> 6;
    int l = rem & 63;
    int nt = F >> 3;
    int s  = (F >> 2) & 1;
    int kt = F & 3;
    int a0 = kt * 32 + (l >> 4) * 8;
    int c  = nt * 16 + (l & 15);
    const float* Wp = W + ((size_t)(n * 2 + s) * CHI + a0) * CHI + c;
    uint4 pk;
    pk.x = f2bf(Wp[0 * CHI]) | (f2bf(Wp[1 * CHI]) << 16);
    pk.y = f2bf(Wp[2 * CHI]) | (f2bf(Wp[3 * CHI]) << 16);
    pk.z = f2bf(Wp[4 * CHI]) | (f2bf(Wp[5 * CHI]) << 16);
    pk.w = f2bf(Wp[6 * CHI]) | (f2bf(Wp[7 * CHI]) << 16);
    ws4[T] = pk;
}

// ---------------------------------------------------------------------------
// main: 64 blocks x 512 threads (8 waves). Block owns 16 batch rows.
// Wave w owns output cols [w*16, w*16+16); its h-slice lives in registers
// (MFMA C-layout) across all 784 sites. Full h mirrored in LDS for A-builds.
// Per site: P_s = bf16(h) @ bf16(W_s)  (2 accs, 4 MFMAs each, K=128),
//           h += x0*P0 + x1*P1 in fp32.
// A-frags built once by waves 0-3, shared via LDS. W frags prefetched 2 sites
// ahead into registers; barriers never drain vmcnt.
// ---------------------------------------------------------------------------
__global__ __launch_bounds__(512) void mps_kernel(const float* __restrict__ x,
                                                  const unsigned short* __restrict__ ws,
                                                  const float* __restrict__ V,
                                                  float* __restrict__ out) {
    __shared__ float hsh[BC * HS];                 // 8448 B, full h (fp32)
    __shared__ unsigned short afr_sh[4 * 64 * 8];  // 4096 B, shared A-frags
    __shared__ float xs[2 * 8 * 32];               // 2048 B, x chunk (dbuf)

    const int t = threadIdx.x;
    const int w = t >> 6, l = t & 63;
    const int m = l & 15, q = l >> 4;
    const int rb = blockIdx.x * BC;

    for (int i = t; i < BC * HS; i += 512) hsh[i] = 1.0f;

    // x chunk staging (every wave redundantly; lanes<32: s = q, row = m)
    const float* xrowp = x + (size_t)(rb + m) * (2 * LL) + (size_t)(q & 1) * LL;
    float4 xra, xrb, xra2, xrb2;
    if (l < 32) {
        xra = *(const float4*)(xrowp + 0);
        xrb = *(const float4*)(xrowp + 4);
        // chunk 0 -> xs[par=0], layout xs[par][site&7][s*16+row]
        float xv[8] = {xra.x, xra.y, xra.z, xra.w, xrb.x, xrb.y, xrb.z, xrb.w};
        #pragma unroll
        for (int k = 0; k < 8; k++) xs[k * 32 + (q & 1) * 16 + m] = xv[k];
        xra2 = *(const float4*)(xrowp + 8);    // chunk 1 in flight
        xrb2 = *(const float4*)(xrowp + 12);
    }
    __syncthreads();

    // wave-private h slice in registers, C-layout: col = w*16+m, row = q*4+i
    floatx4 hacc = (floatx4){1.f, 1.f, 1.f, 1.f};

    // W fragment prefetch: 2 register buffers, 8 frags each (s,kt)
    const unsigned short* wsw = ws + (size_t)w * 4096 + (size_t)(l << 3);
    short8 bA[2][4], bB[2][4];
    #pragma unroll
    for (int s2 = 0; s2 < 2; s2++)
        #pragma unroll
        for (int kt = 0; kt < 4; kt++) {
            bA[s2][kt] = *(const short8*)(wsw + (size_t)0 * 32768 + (s2 * 4 + kt) * 512);
            bB[s2][kt] = *(const short8*)(wsw + (size_t)1 * 32768 + (s2 * 4 + kt) * 512);
        }

#define SITE_BODY(NN, BUF, CHUNKW) do {                                          \
    const int n_ = (NN);                                                         \
    lds_barrier();  /* h writes of prev site visible */                          \
    if ((CHUNKW) && l < 32) {                                                    \
        int par_ = (n_ >> 3) & 1;                                                \
        float xv_[8] = {xra2.x, xra2.y, xra2.z, xra2.w,                          \
                        xrb2.x, xrb2.y, xrb2.z, xrb2.w};                         \
        _Pragma("unroll")                                                        \
        for (int k = 0; k < 8; k++)                                              \
            xs[par_ * 256 + k * 32 + (q & 1) * 16 + m] = xv_[k];                 \
        if (n_ + 8 < LL) {                                                       \
            xra2 = *(const float4*)(xrowp + n_ + 8);                             \
            xrb2 = *(const float4*)(xrowp + n_ + 12);                            \
        }                                                                        \
    }                                                                            \
    if (w < 4) {  /* build A-frag kt=w : A[m][a], a = w*32 + q*8 + j */          \
        int hb_ = m * HS + w * 32 + q * 8;                                       \
        floatx4 h0_ = *(const floatx4*)&hsh[hb_];                                \
        floatx4 h1_ = *(const floatx4*)&hsh[hb_ + 4];                            \
        uint4 pk_;                                                               \
        pk_.x = f2bf(h0_[0]) | (f2bf(h0_[1]) << 16);                             \
        pk_.y = f2bf(h0_[2]) | (f2bf(h0_[3]) << 16);                             \
        pk_.z = f2bf(h1_[0]) | (f2bf(h1_[1]) << 16);                             \
        pk_.w = f2bf(h1_[2]) | (f2bf(h1_[3]) << 16);                             \
        ((uint4*)afr_sh)[w * 64 + l] = pk_;                                      \
    }                                                                            \
    lds_barrier();  /* A-frags + x chunk visible */                              \
    short8 af_[4];                                                               \
    _Pragma("unroll")                                                            \
    for (int kt = 0; kt < 4; kt++) af_[kt] = ((const short8*)afr_sh)[kt * 64 + l];\
    int xb_ = ((n_ >> 3) & 1) * 256 + (n_ & 7) * 32 + q * 4;                     \
    floatx4 x0v_ = *(const floatx4*)&xs[xb_];                                    \
    floatx4 x1v_ = *(const floatx4*)&xs[xb_ + 16];                               \
    floatx4 P0_ = (floatx4){0.f, 0.f, 0.f, 0.f};                                 \
    floatx4 P1_ = (floatx4){0.f, 0.f, 0.f, 0.f};                                 \
    _Pragma("unroll")                                                            \
    for (int kt = 0; kt < 4; kt++) {                                             \
        P0_ = __builtin_amdgcn_mfma_f32_16x16x32_bf16(af_[kt], BUF[0][kt], P0_, 0, 0, 0); \
        P1_ = __builtin_amdgcn_mfma_f32_16x16x32_bf16(af_[kt], BUF[1][kt], P1_, 0, 0, 0); \
    }                                                                            \
    if (n_ + 2 < LL) {  /* refill this buffer with site n+2 */                   \
        _Pragma("unroll")                                                        \
        for (int s2 = 0; s2 < 2; s2++)                                           \
            _Pragma("unroll")                                                    \
            for (int kt = 0; kt < 4; kt++)                                       \
                BUF[s2][kt] = *(const short8*)(wsw + (size_t)(n_ + 2) * 32768 +  \
                                               (s2 * 4 + kt) * 512);             \
    }                                                                            \
    _Pragma("unroll")                                                            \
    for (int i = 0; i < 4; i++)                                                  \
        hacc[i] += x0v_[i] * P0_[i] + x1v_[i] * P1_[i];                          \
    _Pragma("unroll")                                                            \
    for (int i = 0; i < 4; i++)                                                  \
        hsh[(q * 4 + i) * HS + w * 16 + m] = hacc[i];                            \
} while (0)

    for (int n = 0; n < LL; n += 2) {
        SITE_BODY(n, bA, ((n & 7) == 0 && n > 0));
        SITE_BODY(n + 1, bB, false);
    }
#undef SITE_BODY

    __syncthreads();

    // logits = h @ V
    if (t < BC * CLS) {
        int r = t / CLS, cls = t % CLS;
        float sum = 0.f;
        for (int a = 0; a < CHI; a++) sum += hsh[r * HS + a] * V[a * CLS + cls];
        out[(size_t)(rb + r) * CLS + cls] = sum;
    }
}

extern "C" void kernel_launch(void* const* d_in, const int* in_sizes, int n_in,
                              void* d_out, int out_size, void* d_ws, size_t ws_size,
                              hipStream_t stream) {
    const float* x = (const float*)d_in[0];
    const float* W = (const float*)d_in[1];
    const float* V = (const float*)d_in[2];
    float* out = (float*)d_out;

    prep_kernel<<<LL * 16, 256, 0, stream>>>(W, (uint4*)d_ws);
    mps_kernel<<<NBLK, 512, 0, stream>>>(x, (const unsigned short*)d_ws, V, out);
}

// Round 4
// 682.978 us; speedup vs baseline: 2.0400x; 1.1194x over previous
//
#include <hip/hip_runtime.h>

#define LL 784
#define CHI 128
#define CLS 10
#define BC 16
#define NBLK 64          // 1024/16

typedef __attribute__((ext_vector_type(8))) short short8;
typedef __attribute__((ext_vector_type(4))) float floatx4;

__device__ inline unsigned int f2bf(float v) {
    unsigned int u = __float_as_uint(v);
    u += 0x7fffu + ((u >> 16) & 1u);   // RNE
    return u >> 16;
}

// workgroup barrier that does NOT drain vmcnt — keeps W prefetch in flight.
__device__ inline void lds_barrier() {
    asm volatile("s_waitcnt lgkmcnt(0)\n\ts_barrier" ::: "memory");
}

// value from lane^1 (quad_perm [1,0,3,2]) — VALU DPP, no LDS pipe use.
__device__ inline float dpp_xor1(float v) {
    int r = __builtin_amdgcn_update_dpp(0, __float_as_int(v), 0xB1, 0xF, 0xF, true);
    return __int_as_float(r);
}

// ---------------------------------------------------------------------------
// prep: W fp32 (L,2,CHI,CHI) -> bf16 MFMA B-fragments via LDS transpose.
// One block per (n, s, kt): 32a x 128c tile. Coalesced float4 reads,
// fragment-order uint4 writes.
// ws uint4 index: (((n*8 + nt)*2 + s)*4 + kt)*64 + l
//   lane l elem j: value = W[n][s][a = kt*32 + (l>>4)*8 + j][c = nt*16 + (l&15)]
// ---------------------------------------------------------------------------
__global__ __launch_bounds__(256) void prep_kernel(const float* __restrict__ W,
                                                   uint4* __restrict__ ws4) {
    __shared__ float tile[32 * 132];
    const int b = blockIdx.x;            // n*8 + s*4 + kt
    const int n = b >> 3, s = (b >> 2) & 1, kt = b & 3;
    const float* Wp = W + ((size_t)(n * 2 + s) * CHI + kt * 32) * CHI;
    const int t = threadIdx.x;
    #pragma unroll
    for (int k = 0; k < 4; k++) {
        int v = t + k * 256;             // 0..1023 float4s
        int a = v >> 5, c4 = v & 31;
        float4 val = *(const float4*)(Wp + a * CHI + c4 * 4);
        *(float4*)&tile[a * 132 + c4 * 4] = val;
    }
    __syncthreads();
    const int l = t & 63, f0 = t >> 6;
    const int m_ = l & 15, q_ = l >> 4;
    #pragma unroll
    for (int ff = 0; ff < 2; ff++) {
        int nt = f0 + ff * 4;
        const float* tp = &tile[(q_ * 8) * 132 + nt * 16 + m_];
        uint4 pk;
        pk.x = f2bf(tp[0 * 132]) | (f2bf(tp[1 * 132]) << 16);
        pk.y = f2bf(tp[2 * 132]) | (f2bf(tp[3 * 132]) << 16);
        pk.z = f2bf(tp[4 * 132]) | (f2bf(tp[5 * 132]) << 16);
        pk.w = f2bf(tp[6 * 132]) | (f2bf(tp[7 * 132]) << 16);
        ws4[(size_t)(((n * 8 + nt) * 2 + s) * 4 + kt) * 64 + l] = pk;
    }
}

// ---------------------------------------------------------------------------
// main: 64 blocks x 512 threads (8 waves). Block owns 16 batch rows.
// h (fp32, exact) lives in wave registers (C-layout, wave w owns cols
// w*16..w*16+15). bf16 copy of h lives in LDS in A-FRAGMENT layout,
// ping-pong buffered -> ONE lgkmcnt-only barrier per site.
// Per site: af = 4 x ds_read_b128; 4 accs (K split 2+2) x 2 MFMAs;
// hacc += x0*P0 + x1*P1 (fp32); cvt+DPP-pack; even lanes write next frags.
// W frags prefetched 2 sites ahead in registers; x staged 8+ sites ahead.
// ---------------------------------------------------------------------------
__global__ __launch_bounds__(512) void mps_kernel(const float* __restrict__ x,
                                                  const unsigned short* __restrict__ ws,
                                                  const float* __restrict__ V,
                                                  float* __restrict__ out) {
    __shared__ short8 afbuf[2][256];     // [par][kt*64 + l], 2 x 4 KB
    __shared__ float xs[2][8][32];       // [par][site&7][s*16 + row]
    __shared__ float hfin[16 * 132];     // final h for h@V

    const int t = threadIdx.x;
    const int w = t >> 6, l = t & 63;
    const int m = l & 15, q = l >> 4;
    const int rb = blockIdx.x * BC;

    // init afbuf[0] = bf16(1.0)  (1024 uints, 512 threads -> 2 each)
    for (int i = t; i < 1024; i += 512)
        ((unsigned int*)&afbuf[0][0])[i] = 0x3F803F80u;

    // ---- x staging: chunks 0,1 to LDS; chunk 2 in registers ----
    const float* xrowp = x + (size_t)(rb + m) * (2 * LL) + (size_t)(q & 1) * LL;
    float4 xc2a, xc2b;
    if (l < 32) {
        float4 a0 = *(const float4*)(xrowp + 0);
        float4 b0 = *(const float4*)(xrowp + 4);
        float4 a1 = *(const float4*)(xrowp + 8);
        float4 b1 = *(const float4*)(xrowp + 12);
        float v0[8] = {a0.x, a0.y, a0.z, a0.w, b0.x, b0.y, b0.z, b0.w};
        float v1[8] = {a1.x, a1.y, a1.z, a1.w, b1.x, b1.y, b1.z, b1.w};
        #pragma unroll
        for (int k = 0; k < 8; k++) xs[0][k][(q & 1) * 16 + m] = v0[k];
        #pragma unroll
        for (int k = 0; k < 8; k++) xs[1][k][(q & 1) * 16 + m] = v1[k];
        xc2a = *(const float4*)(xrowp + 16);
        xc2b = *(const float4*)(xrowp + 20);
    }

    // ---- W prefetch: 2 register buffers of 8 frags (f = s*4 + kt) ----
    const unsigned short* wsw = ws + (size_t)w * 4096 + (size_t)l * 8;
    short8 bA[8], bB[8];
    #pragma unroll
    for (int f = 0; f < 8; f++) {
        bA[f] = *(const short8*)(wsw + (size_t)0 * 32768 + f * 512);
        bB[f] = *(const short8*)(wsw + (size_t)1 * 32768 + f * 512);
    }

    floatx4 hacc = (floatx4){1.f, 1.f, 1.f, 1.f};
    const int kt_w = w >> 1;
    const int qp_w = (w & 1) * 2 + (m >> 3);
    const int col2 = (m & 7) >> 1;

    __syncthreads();

#define SITE_BODY(NN, BUF) do {                                                   \
    const int n_ = (NN);                                                          \
    lds_barrier();                                                                \
    if ((n_ & 7) == 0 && n_ >= 8 && n_ + 8 < LL && l < 32) {                      \
        int par_ = ((n_ >> 3) + 1) & 1;                                           \
        float xv_[8] = {xc2a.x, xc2a.y, xc2a.z, xc2a.w,                           \
                        xc2b.x, xc2b.y, xc2b.z, xc2b.w};                          \
        _Pragma("unroll")                                                         \
        for (int k = 0; k < 8; k++) xs[par_][k][(q & 1) * 16 + m] = xv_[k];       \
        if (n_ + 16 < LL) {                                                       \
            xc2a = *(const float4*)(xrowp + n_ + 16);                             \
            xc2b = *(const float4*)(xrowp + n_ + 20);                             \
        }                                                                         \
    }                                                                             \
    short8 af0 = afbuf[n_ & 1][0 * 64 + l];                                       \
    short8 af1 = afbuf[n_ & 1][1 * 64 + l];                                       \
    short8 af2 = afbuf[n_ & 1][2 * 64 + l];                                       \
    short8 af3 = afbuf[n_ & 1][3 * 64 + l];                                       \
    floatx4 x0v = *(const floatx4*)&xs[(n_ >> 3) & 1][n_ & 7][q * 4];             \
    floatx4 x1v = *(const floatx4*)&xs[(n_ >> 3) & 1][n_ & 7][16 + q * 4];        \
    floatx4 z = (floatx4){0.f, 0.f, 0.f, 0.f};                                    \
    floatx4 a00 = __builtin_amdgcn_mfma_f32_16x16x32_bf16(af0, BUF[0], z, 0, 0, 0); \
    floatx4 a01 = __builtin_amdgcn_mfma_f32_16x16x32_bf16(af2, BUF[2], z, 0, 0, 0); \
    floatx4 a10 = __builtin_amdgcn_mfma_f32_16x16x32_bf16(af0, BUF[4], z, 0, 0, 0); \
    floatx4 a11 = __builtin_amdgcn_mfma_f32_16x16x32_bf16(af2, BUF[6], z, 0, 0, 0); \
    a00 = __builtin_amdgcn_mfma_f32_16x16x32_bf16(af1, BUF[1], a00, 0, 0, 0);     \
    a01 = __builtin_amdgcn_mfma_f32_16x16x32_bf16(af3, BUF[3], a01, 0, 0, 0);     \
    a10 = __builtin_amdgcn_mfma_f32_16x16x32_bf16(af1, BUF[5], a10, 0, 0, 0);     \
    a11 = __builtin_amdgcn_mfma_f32_16x16x32_bf16(af3, BUF[7], a11, 0, 0, 0);     \
    if (n_ + 2 < LL) {                                                            \
        _Pragma("unroll")                                                         \
        for (int f = 0; f < 8; f++)                                               \
            BUF[f] = *(const short8*)(wsw + (size_t)(n_ + 2) * 32768 + f * 512);  \
    }                                                                             \
    _Pragma("unroll")                                                             \
    for (int i = 0; i < 4; i++)                                                   \
        hacc[i] += x0v[i] * (a00[i] + a01[i]) + x1v[i] * (a10[i] + a11[i]);       \
    float pt0 = dpp_xor1(hacc[0]), pt1 = dpp_xor1(hacc[1]);                       \
    float pt2 = dpp_xor1(hacc[2]), pt3 = dpp_xor1(hacc[3]);                       \
    if (!(m & 1)) {                                                               \
        unsigned int* dst = (unsigned int*)&afbuf[(n_ + 1) & 1][0];               \
        int base_ = (kt_w * 64 + qp_w * 16 + q * 4) * 4 + col2;                   \
        dst[base_ + 0 * 4] = f2bf(hacc[0]) | (f2bf(pt0) << 16);                   \
        dst[base_ + 1 * 4] = f2bf(hacc[1]) | (f2bf(pt1) << 16);                   \
        dst[base_ + 2 * 4] = f2bf(hacc[2]) | (f2bf(pt2) << 16);                   \
        dst[base_ + 3 * 4] = f2bf(hacc[3]) | (f2bf(pt3) << 16);                   \
    }                                                                             \
} while (0)

    for (int n = 0; n < LL; n += 2) {
        SITE_BODY(n, bA);
        SITE_BODY(n + 1, bB);
    }
#undef SITE_BODY

    __syncthreads();

    // hacc (exact fp32) -> LDS, then logits = h @ V
    #pragma unroll
    for (int i = 0; i < 4; i++)
        hfin[(q * 4 + i) * 132 + w * 16 + m] = hacc[i];
    __syncthreads();

    if (t < BC * CLS) {
        int r = t / CLS, cls = t % CLS;
        float sum = 0.f;
        for (int a = 0; a < CHI; a++) sum += hfin[r * 132 + a] * V[a * CLS + cls];
        out[(size_t)(rb + r) * CLS + cls] = sum;
    }
}

extern "C" void kernel_launch(void* const* d_in, const int* in_sizes, int n_in,
                              void* d_out, int out_size, void* d_ws, size_t ws_size,
                              hipStream_t stream) {
    const float* x = (const float*)d_in[0];
    const float* W = (const float*)d_in[1];
    const float* V = (const float*)d_in[2];
    float* out = (float*)d_out;

    prep_kernel<<<LL * 8, 256, 0, stream>>>(W, (uint4*)d_ws);
    mps_kernel<<<NBLK, 512, 0, stream>>>(x, (const unsigned short*)d_ws, V, out);
}